// Round 6
// baseline (141.779 us; speedup 1.0000x reference)
//
#include <hip/hip_runtime.h>

// out[b,o,n] = max_d |x[b,d,n] - w[o,d]| + bias[o]
// B=64, CIN=1024, COUT=1024, N=49. Pixels P = B*N = 3136 = 49*64.
//
// Round-6: identical inner loop to round-5 (pk_sub + v_max3 |.|,|.| asm,
// w scalarized to s_load double-buffered in SGPRs, x double-buffered in VGPRs,
// no LDS/barriers). Change: 128-thread blocks (2 waves, 8 ch each -> 16 ch/block),
// grid = 49 x 64 = 3136 blocks = 12.25/CU  -> tail imbalance 6% (was 14%) and
// ~24 resident waves/CU (was ~15) to cover s_load/global-load latency.

typedef float v2f __attribute__((ext_vector_type(2)));
typedef float v4f __attribute__((ext_vector_type(4)));

constexpr int CIN  = 1024;
constexpr int COUT = 1024;
constexpr int NN   = 49;
constexpr int BB   = 64;
constexpr int P    = BB * NN;     // 3136
constexpr int CPW  = 8;           // channels per wave
constexpr int WPB  = 2;           // waves per block
constexpr int CPB  = CPW * WPB;   // 16 channels per block
constexpr int NT   = CIN / 4;     // 256 k-tiles of 4

#define PKSUB(d, wp, xp) \
    asm("v_pk_add_f32 %0, %1, %2 neg_lo:[0,1] neg_hi:[0,1]" \
        : "=v"(d) : "s"(wp), "v"(xp))
#define AMAX3(a, lo, hi) \
    asm("v_max3_f32 %0, %0, |%1|, |%2|" : "+v"(a) : "v"(lo), "v"(hi))

__global__ __launch_bounds__(128) void ndist_kernel(
    const float* __restrict__ x, const float* __restrict__ w,
    const float* __restrict__ bias, float* __restrict__ out)
{
    const int lane = threadIdx.x & 63;
    const int wid  = __builtin_amdgcn_readfirstlane(threadIdx.x >> 6);

    const int p = blockIdx.y * BB + lane;     // pixel (exact: 3136 = 49*64)
    const int b = p / NN;
    const int n = p - b * NN;
    const int o0 = blockIdx.x * CPB + wid * CPW;

    const float* __restrict__ xrow = x + (size_t)b * CIN * NN + n;
    const float* __restrict__ wb   = w + (size_t)o0 * CIN;   // wave-uniform base

    float acc[CPW];
#pragma unroll
    for (int c = 0; c < CPW; ++c) acc[c] = 0.0f;   // |diff| >= 0

    // --- double buffers ---
    v2f xA[2], xB[2];           // x k-pairs (VGPR pairs)
    v2f wA[CPW][2], wB[CPW][2]; // w k-pairs (SGPR pairs via s_load_dwordx4)

#define LOAD_X(dst, kt) do {                                   \
        float _x0 = xrow[((kt) * 4 + 0) * NN];                 \
        float _x1 = xrow[((kt) * 4 + 1) * NN];                 \
        float _x2 = xrow[((kt) * 4 + 2) * NN];                 \
        float _x3 = xrow[((kt) * 4 + 3) * NN];                 \
        dst[0] = (v2f){_x0, _x1};                              \
        dst[1] = (v2f){_x2, _x3};                              \
    } while (0)

#define LOAD_W(dst, kt) do {                                   \
        _Pragma("unroll")                                      \
        for (int c = 0; c < CPW; ++c) {                        \
            v4f t = *(const v4f*)(wb + (size_t)c * CIN + (kt) * 4); \
            dst[c][0] = (v2f){t.x, t.y};                       \
            dst[c][1] = (v2f){t.z, t.w};                       \
        }                                                      \
    } while (0)

#define COMPUTE(xv, wv) do {                                   \
        _Pragma("unroll")                                      \
        for (int c = 0; c < CPW; ++c) {                        \
            v2f d0, d1;                                        \
            PKSUB(d0, wv[c][0], xv[0]);                        \
            PKSUB(d1, wv[c][1], xv[1]);                        \
            AMAX3(acc[c], d0.x, d0.y);                         \
            AMAX3(acc[c], d1.x, d1.y);                         \
        }                                                      \
    } while (0)

    LOAD_X(xA, 0);
    LOAD_W(wA, 0);

    for (int kt = 0; kt < NT; kt += 2) {
        // prefetch tile kt+1, compute tile kt
        LOAD_X(xB, kt + 1);
        LOAD_W(wB, kt + 1);
        COMPUTE(xA, wA);

        // prefetch tile kt+2 (wrap on last iter; harmless redundant load)
        const int ktn = (kt + 2) & (NT - 1);
        LOAD_X(xA, ktn);
        LOAD_W(wA, ktn);
        COMPUTE(xB, wB);
    }

#pragma unroll
    for (int c = 0; c < CPW; ++c) {
        const int o = o0 + c;
        out[((size_t)b * COUT + o) * NN + n] = acc[c] + bias[o];  // bias: s_load
    }
}

extern "C" void kernel_launch(void* const* d_in, const int* in_sizes, int n_in,
                              void* d_out, int out_size, void* d_ws, size_t ws_size,
                              hipStream_t stream) {
    const float* x    = (const float*)d_in[0];
    const float* w    = (const float*)d_in[1];
    const float* bias = (const float*)d_in[2];
    float* out        = (float*)d_out;

    dim3 grid(COUT / CPB, P / BB);   // (64 channel-groups, 49 pixel-tiles) = 3136 blocks
    ndist_kernel<<<grid, 128, 0, stream>>>(x, w, bias, out);
}